// Round 1
// baseline (268.139 us; speedup 1.0000x reference)
//
#include <hip/hip_runtime.h>
#include <hip/hip_bf16.h>

// MTPAttention: B=2,S=2048,HS=1024,H=16,KV=4,DH=64, full attention + additive mask.
// Pipeline: convert/pack -> GEMM(QKV) -> RMS-norm(Q,K) -> flash attn -> GEMM(O@wo).

typedef __attribute__((ext_vector_type(8))) short short8_t;   // 8 x bf16 (4 VGPR)
typedef __attribute__((ext_vector_type(4))) float f32x4_t;    // MFMA acc

__device__ __forceinline__ unsigned short f2bf_bits(float x) {
  unsigned int u = __float_as_uint(x);
  unsigned int r = u + 0x7fff + ((u >> 16) & 1);   // RNE (inputs finite)
  return (unsigned short)(r >> 16);
}
__device__ __forceinline__ float bf2f_bits(unsigned short b) {
  return __uint_as_float(((unsigned int)b) << 16);
}

__device__ __forceinline__ void async16(void* lds, const void* g) {
  __builtin_amdgcn_global_load_lds(
      (const __attribute__((address_space(1))) void*)g,
      (__attribute__((address_space(3))) void*)lds, 16, 0, 0);
}

// ---------------- convert fp32 -> bf16 (vectorized) ----------------
__global__ __launch_bounds__(256) void convert_f32_bf16(
    const float* __restrict__ in, unsigned short* __restrict__ out, int n) {
  int i = (blockIdx.x * 256 + threadIdx.x) * 4;
  if (i >= n) return;
  float4 v = *(const float4*)(in + i);
  ushort4 o;
  o.x = f2bf_bits(v.x); o.y = f2bf_bits(v.y);
  o.z = f2bf_bits(v.z); o.w = f2bf_bits(v.w);
  *(ushort4*)(out + i) = o;
}

// ---------------- transpose + convert weights: W[K=1024][Nsrc] -> Wt[n_off+n][k] bf16 ----------------
__global__ __launch_bounds__(256) void transpose_pack(
    const float* __restrict__ W, unsigned short* __restrict__ Wt, int Nsrc, int n_off) {
  __shared__ unsigned short T[64][72];   // +8 pad: conflict-free both phases
  const int tn = blockIdx.x * 64, tk = blockIdx.y * 64;
  for (int e = threadIdx.x; e < 4096; e += 256) {
    int kk = e >> 6, nn = e & 63;
    T[nn][kk] = f2bf_bits(W[(size_t)(tk + kk) * Nsrc + tn + nn]);   // coalesced read
  }
  __syncthreads();
  for (int e = threadIdx.x; e < 4096; e += 256) {
    int nn = e >> 6, kk = e & 63;
    Wt[(size_t)(n_off + tn + nn) * 1024 + tk + kk] = T[nn][kk];     // coalesced write
  }
}

// ---------------- bf16 GEMM: C[M][N] = A[M][K] * Bt[N][K]^T  (m97 structure) ----------------
template <bool OUT_BF16>
__global__ __launch_bounds__(256) void gemm_bt(
    const unsigned short* __restrict__ A, const unsigned short* __restrict__ Bt,
    void* __restrict__ Cp, int M, int N, int K, int ldc) {
  __shared__ unsigned short As[128 * 32];   // [row][k] 64B rows
  __shared__ unsigned short Bs[128 * 32];   // [n][k]
  const int tid = threadIdx.x;
  const int w = tid >> 6, l = tid & 63, lr = l & 15, lg = l >> 4;
  const int bm = blockIdx.y * 128, bn = blockIdx.x * 128;
  const int wrow = (w >> 1) * 64, wcol = (w & 1) * 64;

  f32x4_t acc[4][4] = {};

  for (int k0 = 0; k0 < K; k0 += 32) {
    __syncthreads();   // prev frag reads done before overwrite
    #pragma unroll
    for (int i = 0; i < 2; ++i) {
      int c = i * 4 + w;  // chunk id 0..7, wave-uniform
      const unsigned short* ga = A + (size_t)(bm + c * 16 + (l >> 2)) * K + k0 + (l & 3) * 8;
      async16(As + c * 512, ga);
      const unsigned short* gb = Bt + (size_t)(bn + c * 16 + (l >> 2)) * K + k0 + (l & 3) * 8;
      async16(Bs + c * 512, gb);
    }
    __syncthreads();   // drains vmcnt
    short8_t af[4], bfr[4];
    #pragma unroll
    for (int m = 0; m < 4; ++m)
      af[m] = *(const short8_t*)(As + (wrow + m * 16 + lr) * 32 + lg * 8);
    #pragma unroll
    for (int n = 0; n < 4; ++n)
      bfr[n] = *(const short8_t*)(Bs + (wcol + n * 16 + lr) * 32 + lg * 8);
    #pragma unroll
    for (int m = 0; m < 4; ++m)
      #pragma unroll
      for (int n = 0; n < 4; ++n)
        acc[m][n] = __builtin_amdgcn_mfma_f32_16x16x32_bf16(af[m], bfr[n], acc[m][n], 0, 0, 0);
  }

  #pragma unroll
  for (int m = 0; m < 4; ++m)
    #pragma unroll
    for (int n = 0; n < 4; ++n)
      #pragma unroll
      for (int j = 0; j < 4; ++j) {
        int row = bm + wrow + m * 16 + lg * 4 + j;   // verified D layout (m89)
        int col = bn + wcol + n * 16 + lr;
        float v = acc[m][n][j];
        if (OUT_BF16) ((unsigned short*)Cp)[(size_t)row * ldc + col] = f2bf_bits(v);
        else          ((float*)Cp)[(size_t)row * ldc + col] = v;
      }
}

// ---------------- RMS norm over DH=64 for Q (16 heads) and K (4 heads), in place ----------------
__global__ __launch_bounds__(256) void qk_norm(
    unsigned short* __restrict__ qkv, const float* __restrict__ qw, const float* __restrict__ kw) {
  int gid = blockIdx.x * 4 + (threadIdx.x >> 6);   // (row, seg) pair, one wave each
  int l = threadIdx.x & 63;
  int row = gid / 20, seg = gid - row * 20;        // seg 0..15 = Q heads, 16..19 = K heads
  size_t idx = (size_t)row * 1536 + seg * 64 + l;
  float x = bf2f_bits(qkv[idx]);
  float ss = x * x;
  #pragma unroll
  for (int m = 1; m < 64; m <<= 1) ss += __shfl_xor(ss, m, 64);
  float r = rsqrtf(ss * (1.0f / 64.0f) + 1e-6f);
  float wv = (seg < 16) ? qw[l] : kw[l];
  qkv[idx] = f2bf_bits(x * r * wv);
}

// ---------------- flash attention: block = (64-row q-tile, b, hq) ----------------
__global__ __launch_bounds__(256) void flash_attn(
    const unsigned short* __restrict__ qkv, const float* __restrict__ mask,
    unsigned short* __restrict__ O) {
  const int qt = blockIdx.x;            // 0..31
  const int bh = blockIdx.y;            // 0..31
  const int b = bh >> 4, hq = bh & 15, kvh = hq >> 2;
  const int tid = threadIdx.x, w = tid >> 6, l = tid & 63, lr = l & 15, lg = l >> 4;

  __shared__ unsigned short Qs[64 * 72];   // [q][d]   pad->144B rows (16B aligned)
  __shared__ unsigned short Ks[64 * 72];   // [k][d]
  __shared__ unsigned short Vt[64 * 72];   // [d][k]  (transposed at staging)
  __shared__ unsigned short Ps[64 * 72];   // [q][k]

  const unsigned short* Qg = qkv + (size_t)(b * 2048 + qt * 64) * 1536 + hq * 64;
  const unsigned short* Kg = qkv + (size_t)(b * 2048) * 1536 + 1024 + kvh * 64;
  const unsigned short* Vg = Kg + 256;
  const float* Mg = mask + (size_t)(qt * 64) * 2048;

  // stage Q once
  for (int e = tid * 8; e < 4096; e += 2048) {
    int r = e >> 6, c = e & 63;
    *(short8_t*)(Qs + r * 72 + c) = *(const short8_t*)(Qg + (size_t)r * 1536 + c);
  }
  __syncthreads();
  short8_t qf[2];
  qf[0] = *(const short8_t*)(Qs + (w * 16 + lr) * 72 + lg * 8);
  qf[1] = *(const short8_t*)(Qs + (w * 16 + lr) * 72 + 32 + lg * 8);

  f32x4_t oacc[4] = {};
  float mrun[4] = {-INFINITY, -INFINITY, -INFINITY, -INFINITY};
  float lrun[4] = {0.f, 0.f, 0.f, 0.f};
  const float L2E = 1.44269504f;

  for (int kt = 0; kt < 32; ++kt) {
    __syncthreads();   // prev iter's LDS reads done
    for (int e = tid * 8; e < 4096; e += 2048) {     // K tile, row-major
      int r = e >> 6, c = e & 63;
      *(short8_t*)(Ks + r * 72 + c) = *(const short8_t*)(Kg + (size_t)(kt * 64 + r) * 1536 + c);
    }
    for (int e = tid; e < 4096; e += 256) {          // V tile, transposed
      int k = e >> 6, d = e & 63;
      Vt[d * 72 + k] = Vg[(size_t)(kt * 64 + k) * 1536 + d];
    }
    __syncthreads();

    // S = Q K^T (wave: 16 q-rows x 64 k-cols)
    f32x4_t sacc[4] = {};
    #pragma unroll
    for (int kd = 0; kd < 2; ++kd)
      #pragma unroll
      for (int n = 0; n < 4; ++n) {
        short8_t bfr = *(const short8_t*)(Ks + (n * 16 + lr) * 72 + kd * 32 + lg * 8);
        sacc[n] = __builtin_amdgcn_mfma_f32_16x16x32_bf16(qf[kd], bfr, sacc[n], 0, 0, 0);
      }

    // scale + mask + online softmax (rows lg*4+j; reduce over 16-lane col groups)
    float p[4][4], rm[4];
    #pragma unroll
    for (int j = 0; j < 4; ++j) rm[j] = -INFINITY;
    #pragma unroll
    for (int n = 0; n < 4; ++n)
      #pragma unroll
      for (int j = 0; j < 4; ++j) {
        float s = sacc[n][j] * 0.125f
                + Mg[(size_t)(w * 16 + lg * 4 + j) * 2048 + kt * 64 + n * 16 + lr];
        p[n][j] = s;
        rm[j] = fmaxf(rm[j], s);
      }
    #pragma unroll
    for (int j = 0; j < 4; ++j) {
      #pragma unroll
      for (int m = 1; m < 16; m <<= 1) rm[j] = fmaxf(rm[j], __shfl_xor(rm[j], m, 64));
    }
    float alpha[4], rs[4];
    #pragma unroll
    for (int j = 0; j < 4; ++j) {
      float mn = fmaxf(mrun[j], rm[j]);
      alpha[j] = exp2f((mrun[j] - mn) * L2E);
      mrun[j] = mn;
      rs[j] = 0.f;
    }
    #pragma unroll
    for (int n = 0; n < 4; ++n)
      #pragma unroll
      for (int j = 0; j < 4; ++j) {
        float e = exp2f((p[n][j] - mrun[j]) * L2E);
        p[n][j] = e;
        rs[j] += e;
      }
    #pragma unroll
    for (int j = 0; j < 4; ++j) {
      #pragma unroll
      for (int m = 1; m < 16; m <<= 1) rs[j] += __shfl_xor(rs[j], m, 64);
      lrun[j] = lrun[j] * alpha[j] + rs[j];
    }
    #pragma unroll
    for (int n = 0; n < 4; ++n) {
      f32x4_t t = oacc[n];
      #pragma unroll
      for (int j = 0; j < 4; ++j) t[j] *= alpha[j];
      oacc[n] = t;
    }

    // P -> LDS (own wave's rows only)
    #pragma unroll
    for (int n = 0; n < 4; ++n)
      #pragma unroll
      for (int j = 0; j < 4; ++j)
        Ps[(w * 16 + lg * 4 + j) * 72 + n * 16 + lr] = f2bf_bits(p[n][j]);
    __syncthreads();   // conservative: order P writes before A-frag reads

    // O += P V
    #pragma unroll
    for (int kd = 0; kd < 2; ++kd) {
      short8_t pa = *(const short8_t*)(Ps + (w * 16 + lr) * 72 + kd * 32 + lg * 8);
      #pragma unroll
      for (int nd = 0; nd < 4; ++nd) {
        short8_t vb = *(const short8_t*)(Vt + (nd * 16 + lr) * 72 + kd * 32 + lg * 8);
        oacc[nd] = __builtin_amdgcn_mfma_f32_16x16x32_bf16(pa, vb, oacc[nd], 0, 0, 0);
      }
    }
  }

  // epilogue: O /= l, write bf16 [4096][1024] at col hq*64
  #pragma unroll
  for (int nd = 0; nd < 4; ++nd)
    #pragma unroll
    for (int j = 0; j < 4; ++j) {
      size_t row = (size_t)(b * 2048 + qt * 64 + w * 16 + lg * 4 + j);
      O[row * 1024 + hq * 64 + nd * 16 + lr] = f2bf_bits(oacc[nd][j] / lrun[j]);
    }
}

extern "C" void kernel_launch(void* const* d_in, const int* in_sizes, int n_in,
                              void* d_out, int out_size, void* d_ws, size_t ws_size,
                              hipStream_t stream) {
  const float* hidden = (const float*)d_in[0];
  const float* mask   = (const float*)d_in[1];
  const float* wq     = (const float*)d_in[2];
  const float* wk     = (const float*)d_in[3];
  const float* wv     = (const float*)d_in[4];
  const float* wo     = (const float*)d_in[5];
  const float* qw     = (const float*)d_in[6];
  const float* kw     = (const float*)d_in[7];

  char* ws = (char*)d_ws;
  unsigned short* Xbf   = (unsigned short*)(ws);              // [4096][1024] bf16 (aliased by Obf later)
  unsigned short* Wqkvt = (unsigned short*)(ws +  8388608);   // [1536][1024] bf16 (wq|wk|wv transposed)
  unsigned short* Wot   = (unsigned short*)(ws + 11534336);   // [1024][1024] bf16
  unsigned short* QKV   = (unsigned short*)(ws + 13631488);   // [4096][1536] bf16
  unsigned short* Obf   = Xbf;                                // X dead after GEMM1

  convert_f32_bf16<<<4096, 256, 0, stream>>>(hidden, Xbf, 4096 * 1024);
  transpose_pack<<<dim3(16, 16), 256, 0, stream>>>(wq, Wqkvt, 1024, 0);
  transpose_pack<<<dim3(4, 16),  256, 0, stream>>>(wk, Wqkvt, 256, 1024);
  transpose_pack<<<dim3(4, 16),  256, 0, stream>>>(wv, Wqkvt, 256, 1280);
  transpose_pack<<<dim3(16, 16), 256, 0, stream>>>(wo, Wot, 1024, 0);

  gemm_bt<true><<<dim3(12, 32), 256, 0, stream>>>(Xbf, Wqkvt, QKV, 4096, 1536, 1024, 1536);
  qk_norm<<<20480, 256, 0, stream>>>(QKV, qw, kw);
  flash_attn<<<dim3(32, 32), 256, 0, stream>>>(QKV, mask, Obf);
  gemm_bt<false><<<dim3(8, 32), 256, 0, stream>>>(Obf, Wot, d_out, 4096, 1024, 1024, 1024);
}

// Round 2
// 236.223 us; speedup vs baseline: 1.1351x; 1.1351x over previous
//
#include <hip/hip_runtime.h>
#include <hip/hip_bf16.h>

// MTPAttention: B=2,S=2048,HS=1024,H=16,KV=4,DH=64, full attention + additive mask.
// Pipeline: convert/pack -> GEMM(QKV) -> qk_norm(+fold scale) -> V-transpose ->
//           mask tile-zero bitmap -> flash attn -> GEMM(O@wo).

typedef __attribute__((ext_vector_type(8))) short short8_t;   // 8 x bf16 (4 VGPR)
typedef __attribute__((ext_vector_type(4))) float f32x4_t;    // MFMA acc

__device__ __forceinline__ unsigned short f2bf_bits(float x) {
  unsigned int u = __float_as_uint(x);
  unsigned int r = u + 0x7fff + ((u >> 16) & 1);   // RNE (inputs finite)
  return (unsigned short)(r >> 16);
}
__device__ __forceinline__ float bf2f_bits(unsigned short b) {
  return __uint_as_float(((unsigned int)b) << 16);
}

__device__ __forceinline__ void async16(void* lds, const void* g) {
  __builtin_amdgcn_global_load_lds(
      (const __attribute__((address_space(1))) void*)g,
      (__attribute__((address_space(3))) void*)lds, 16, 0, 0);
}

// ---------------- convert fp32 -> bf16 (vectorized) ----------------
__global__ __launch_bounds__(256) void convert_f32_bf16(
    const float* __restrict__ in, unsigned short* __restrict__ out, int n) {
  int i = (blockIdx.x * 256 + threadIdx.x) * 4;
  if (i >= n) return;
  float4 v = *(const float4*)(in + i);
  ushort4 o;
  o.x = f2bf_bits(v.x); o.y = f2bf_bits(v.y);
  o.z = f2bf_bits(v.z); o.w = f2bf_bits(v.w);
  *(ushort4*)(out + i) = o;
}

// ---------------- transpose + convert weights: W[K=1024][Nsrc] -> Wt[n_off+n][k] bf16 ----------------
__global__ __launch_bounds__(256) void transpose_pack(
    const float* __restrict__ W, unsigned short* __restrict__ Wt, int Nsrc, int n_off) {
  __shared__ unsigned short T[64][72];
  const int tn = blockIdx.x * 64, tk = blockIdx.y * 64;
  for (int e = threadIdx.x; e < 4096; e += 256) {
    int kk = e >> 6, nn = e & 63;
    T[nn][kk] = f2bf_bits(W[(size_t)(tk + kk) * Nsrc + tn + nn]);   // coalesced read
  }
  __syncthreads();
  for (int e = threadIdx.x; e < 4096; e += 256) {
    int nn = e >> 6, kk = e & 63;
    Wt[(size_t)(n_off + tn + nn) * 1024 + tk + kk] = T[nn][kk];     // coalesced write
  }
}

// ---------------- transpose V: QKV[row][1280+kvh*64+d] -> Vt[(b*4+kvh)*64+d][s] ----------------
__global__ __launch_bounds__(256) void transpose_v(
    const unsigned short* __restrict__ qkv, unsigned short* __restrict__ vt) {
  __shared__ unsigned short T[64][72];
  const int tid = threadIdx.x;
  const int st = blockIdx.x * 64, bk = blockIdx.y;      // bk = b*4+kvh
  const int b = bk >> 2, kvh = bk & 3;
  const unsigned short* src = qkv + (size_t)(b * 2048 + st) * 1536 + 1280 + kvh * 64;
  for (int e = tid; e < 4096; e += 256) {
    int s = e >> 6, d = e & 63;
    T[d][s] = src[(size_t)s * 1536 + d];                // coalesced read
  }
  __syncthreads();
  unsigned short* dst = vt + (size_t)bk * 64 * 2048 + st;
  for (int e = tid; e < 4096; e += 256) {
    int d = e >> 6, s = e & 63;
    dst[(size_t)d * 2048 + s] = T[d][s];                // coalesced write
  }
}

// ---------------- mask tile-zero bitmap: flags[qt*32+kt] = any nonzero in 64x64 tile ----------------
__global__ __launch_bounds__(256) void mask_flags(
    const float* __restrict__ mask, int* __restrict__ flags) {
  const int tid = threadIdx.x;
  const int bq = blockIdx.y * 64, bk = blockIdx.x * 64;
  bool nz = false;
  #pragma unroll
  for (int i = 0; i < 4; ++i) {
    int e = (i * 256 + tid) * 4;                        // float4 index over 4096
    int r = e >> 6, c = e & 63;
    float4 v = *(const float4*)(mask + (size_t)(bq + r) * 2048 + bk + c);
    nz |= (v.x != 0.f) | (v.y != 0.f) | (v.z != 0.f) | (v.w != 0.f);
  }
  __shared__ int s;
  if (tid == 0) s = 0;
  __syncthreads();
  if (__any((int)nz) && (tid & 63) == 0) atomicOr(&s, 1);
  __syncthreads();
  if (tid == 0) flags[blockIdx.y * gridDim.x + blockIdx.x] = s;
}

// ---------------- bf16 GEMM: C[M][N] = A[M][K] * Bt[N][K]^T  (m97 structure) ----------------
template <bool OUT_BF16>
__global__ __launch_bounds__(256) void gemm_bt(
    const unsigned short* __restrict__ A, const unsigned short* __restrict__ Bt,
    void* __restrict__ Cp, int M, int N, int K, int ldc) {
  __shared__ unsigned short As[128 * 32];
  __shared__ unsigned short Bs[128 * 32];
  const int tid = threadIdx.x;
  const int w = tid >> 6, l = tid & 63, lr = l & 15, lg = l >> 4;
  const int bm = blockIdx.y * 128, bn = blockIdx.x * 128;
  const int wrow = (w >> 1) * 64, wcol = (w & 1) * 64;

  f32x4_t acc[4][4] = {};

  for (int k0 = 0; k0 < K; k0 += 32) {
    __syncthreads();
    #pragma unroll
    for (int i = 0; i < 2; ++i) {
      int c = i * 4 + w;
      const unsigned short* ga = A + (size_t)(bm + c * 16 + (l >> 2)) * K + k0 + (l & 3) * 8;
      async16(As + c * 512, ga);
      const unsigned short* gb = Bt + (size_t)(bn + c * 16 + (l >> 2)) * K + k0 + (l & 3) * 8;
      async16(Bs + c * 512, gb);
    }
    __syncthreads();
    short8_t af[4], bfr[4];
    #pragma unroll
    for (int m = 0; m < 4; ++m)
      af[m] = *(const short8_t*)(As + (wrow + m * 16 + lr) * 32 + lg * 8);
    #pragma unroll
    for (int n = 0; n < 4; ++n)
      bfr[n] = *(const short8_t*)(Bs + (wcol + n * 16 + lr) * 32 + lg * 8);
    #pragma unroll
    for (int m = 0; m < 4; ++m)
      #pragma unroll
      for (int n = 0; n < 4; ++n)
        acc[m][n] = __builtin_amdgcn_mfma_f32_16x16x32_bf16(af[m], bfr[n], acc[m][n], 0, 0, 0);
  }

  #pragma unroll
  for (int m = 0; m < 4; ++m)
    #pragma unroll
    for (int n = 0; n < 4; ++n)
      #pragma unroll
      for (int j = 0; j < 4; ++j) {
        int row = bm + wrow + m * 16 + lg * 4 + j;
        int col = bn + wcol + n * 16 + lr;
        float v = acc[m][n][j];
        if (OUT_BF16) ((unsigned short*)Cp)[(size_t)row * ldc + col] = f2bf_bits(v);
        else          ((float*)Cp)[(size_t)row * ldc + col] = v;
      }
}

// ---------------- RMS norm over DH=64; Q heads also fold in SCALE=0.125 ----------------
__global__ __launch_bounds__(256) void qk_norm(
    unsigned short* __restrict__ qkv, const float* __restrict__ qw, const float* __restrict__ kw) {
  int gid = blockIdx.x * 4 + (threadIdx.x >> 6);
  int l = threadIdx.x & 63;
  int row = gid / 20, seg = gid - row * 20;        // 0..15 = Q heads, 16..19 = K heads
  size_t idx = (size_t)row * 1536 + seg * 64 + l;
  float x = bf2f_bits(qkv[idx]);
  float ss = x * x;
  #pragma unroll
  for (int m = 1; m < 64; m <<= 1) ss += __shfl_xor(ss, m, 64);
  float r = rsqrtf(ss * (1.0f / 64.0f) + 1e-6f);
  float wv = (seg < 16) ? qw[l] * 0.125f : kw[l];   // fold attention scale into Q
  qkv[idx] = f2bf_bits(x * r * wv);
}

// ---------------- flash attention: block = (64-row q-tile, b, hq) ----------------
__global__ __launch_bounds__(256) void flash_attn(
    const unsigned short* __restrict__ qkv, const unsigned short* __restrict__ vtg,
    const float* __restrict__ mask, const int* __restrict__ flags,
    unsigned short* __restrict__ O) {
  const int qt = blockIdx.x;            // 0..31
  const int bh = blockIdx.y;            // 0..31
  const int b = bh >> 4, hq = bh & 15, kvh = hq >> 2;
  const int tid = threadIdx.x, w = tid >> 6, l = tid & 63, lr = l & 15, lg = l >> 4;

  __shared__ unsigned short Qs[64 * 72];   // [q][d]
  __shared__ unsigned short Ks[64 * 72];   // [k][d]
  __shared__ unsigned short Vs[64 * 72];   // [d][k]  (from pre-transposed Vt)
  __shared__ unsigned short Ps[64 * 72];   // [q][k]

  const unsigned short* Qg = qkv + (size_t)(b * 2048 + qt * 64) * 1536 + hq * 64;
  const unsigned short* Kg = qkv + (size_t)(b * 2048) * 1536 + 1024 + kvh * 64;
  const unsigned short* Vg = vtg + (size_t)(b * 4 + kvh) * 64 * 2048;
  const float* Mg = mask + (size_t)(qt * 64) * 2048;

  // stage Q once
  for (int e = tid * 8; e < 4096; e += 2048) {
    int r = e >> 6, c = e & 63;
    *(short8_t*)(Qs + r * 72 + c) = *(const short8_t*)(Qg + (size_t)r * 1536 + c);
  }
  __syncthreads();
  short8_t qf[2];
  qf[0] = *(const short8_t*)(Qs + (w * 16 + lr) * 72 + lg * 8);
  qf[1] = *(const short8_t*)(Qs + (w * 16 + lr) * 72 + 32 + lg * 8);

  f32x4_t oacc[4] = {};
  float mrun[4] = {-INFINITY, -INFINITY, -INFINITY, -INFINITY};
  float lrun[4] = {0.f, 0.f, 0.f, 0.f};
  const float L2E = 1.44269504f;

  for (int kt = 0; kt < 32; ++kt) {
    __syncthreads();
    // K tile [k][d], vectorized
    for (int e = tid * 8; e < 4096; e += 2048) {
      int r = e >> 6, c = e & 63;
      *(short8_t*)(Ks + r * 72 + c) = *(const short8_t*)(Kg + (size_t)(kt * 64 + r) * 1536 + c);
    }
    // V tile [d][k], vectorized from pre-transposed global
    #pragma unroll
    for (int i = 0; i < 2; ++i) {
      int c = i * 256 + tid;                 // 16B chunk id 0..511
      int d = c >> 3, s8 = (c & 7) * 8;
      *(short8_t*)(Vs + d * 72 + s8) = *(const short8_t*)(Vg + (size_t)d * 2048 + kt * 64 + s8);
    }
    __syncthreads();

    // S = Q K^T (wave: 16 q-rows x 64 k-cols); scale pre-folded into Q
    f32x4_t sacc[4] = {};
    #pragma unroll
    for (int kd = 0; kd < 2; ++kd)
      #pragma unroll
      for (int n = 0; n < 4; ++n) {
        short8_t bfr = *(const short8_t*)(Ks + (n * 16 + lr) * 72 + kd * 32 + lg * 8);
        sacc[n] = __builtin_amdgcn_mfma_f32_16x16x32_bf16(qf[kd], bfr, sacc[n], 0, 0, 0);
      }

    float p[4][4];
    if (flags[qt * 32 + kt]) {
      #pragma unroll
      for (int n = 0; n < 4; ++n)
        #pragma unroll
        for (int j = 0; j < 4; ++j)
          p[n][j] = sacc[n][j]
                  + Mg[(size_t)(w * 16 + lg * 4 + j) * 2048 + kt * 64 + n * 16 + lr];
    } else {
      #pragma unroll
      for (int n = 0; n < 4; ++n)
        #pragma unroll
        for (int j = 0; j < 4; ++j)
          p[n][j] = sacc[n][j];
    }

    // per-row max (fused max tree + 16-lane butterfly)
    float rm[4];
    #pragma unroll
    for (int j = 0; j < 4; ++j) {
      rm[j] = fmaxf(fmaxf(fmaxf(p[0][j], p[1][j]), p[2][j]), p[3][j]);
      #pragma unroll
      for (int m = 1; m < 16; m <<= 1) rm[j] = fmaxf(rm[j], __shfl_xor(rm[j], m, 64));
    }

    // deferred rescale (T13, THR=8)
    bool need = (rm[0] > mrun[0] + 8.f) | (rm[1] > mrun[1] + 8.f) |
                (rm[2] > mrun[2] + 8.f) | (rm[3] > mrun[3] + 8.f);
    if (__any((int)need)) {
      float al[4];
      #pragma unroll
      for (int j = 0; j < 4; ++j) {
        float mn = fmaxf(mrun[j], rm[j]);
        al[j] = exp2f((mrun[j] - mn) * L2E);
        mrun[j] = mn;
        lrun[j] *= al[j];
      }
      #pragma unroll
      for (int nd = 0; nd < 4; ++nd) {
        f32x4_t t = oacc[nd];
        #pragma unroll
        for (int j = 0; j < 4; ++j) t[j] *= al[j];
        oacc[nd] = t;
      }
    }

    float nm[4], rs[4];
    #pragma unroll
    for (int j = 0; j < 4; ++j) { nm[j] = -mrun[j] * L2E; rs[j] = 0.f; }
    #pragma unroll
    for (int n = 0; n < 4; ++n)
      #pragma unroll
      for (int j = 0; j < 4; ++j) {
        float e = exp2f(fmaf(p[n][j], L2E, nm[j]));
        p[n][j] = e;
        rs[j] += e;
      }
    #pragma unroll
    for (int j = 0; j < 4; ++j) {
      #pragma unroll
      for (int m = 1; m < 16; m <<= 1) rs[j] += __shfl_xor(rs[j], m, 64);
      lrun[j] += rs[j];
    }

    // P -> LDS (own wave's rows only)
    #pragma unroll
    for (int n = 0; n < 4; ++n)
      #pragma unroll
      for (int j = 0; j < 4; ++j)
        Ps[(w * 16 + lg * 4 + j) * 72 + n * 16 + lr] = f2bf_bits(p[n][j]);
    __syncthreads();

    // O += P V
    #pragma unroll
    for (int kd = 0; kd < 2; ++kd) {
      short8_t pa = *(const short8_t*)(Ps + (w * 16 + lr) * 72 + kd * 32 + lg * 8);
      #pragma unroll
      for (int nd = 0; nd < 4; ++nd) {
        short8_t vb = *(const short8_t*)(Vs + (nd * 16 + lr) * 72 + kd * 32 + lg * 8);
        oacc[nd] = __builtin_amdgcn_mfma_f32_16x16x32_bf16(pa, vb, oacc[nd], 0, 0, 0);
      }
    }
  }

  // epilogue: O /= l, write bf16 [4096][1024] at col hq*64
  #pragma unroll
  for (int nd = 0; nd < 4; ++nd)
    #pragma unroll
    for (int j = 0; j < 4; ++j) {
      size_t row = (size_t)(b * 2048 + qt * 64 + w * 16 + lg * 4 + j);
      O[row * 1024 + hq * 64 + nd * 16 + lr] = f2bf_bits(oacc[nd][j] / lrun[j]);
    }
}

extern "C" void kernel_launch(void* const* d_in, const int* in_sizes, int n_in,
                              void* d_out, int out_size, void* d_ws, size_t ws_size,
                              hipStream_t stream) {
  const float* hidden = (const float*)d_in[0];
  const float* mask   = (const float*)d_in[1];
  const float* wq     = (const float*)d_in[2];
  const float* wk     = (const float*)d_in[3];
  const float* wv     = (const float*)d_in[4];
  const float* wo     = (const float*)d_in[5];
  const float* qw     = (const float*)d_in[6];
  const float* kw     = (const float*)d_in[7];

  char* ws = (char*)d_ws;
  unsigned short* Xbf   = (unsigned short*)(ws);              // [4096][1024] bf16
  unsigned short* Wqkvt = (unsigned short*)(ws +  8388608);   // [1536][1024] bf16 (dead after gemm1)
  unsigned short* Wot   = (unsigned short*)(ws + 11534336);   // [1024][1024] bf16
  unsigned short* QKV   = (unsigned short*)(ws + 13631488);   // [4096][1536] bf16
  unsigned short* Vtg   = Wqkvt;                              // [8*64][2048] bf16, aliases Wqkvt
  int*            flags = (int*)(ws + 10485760);              // [1024], aliases Wqkvt tail
  unsigned short* Obf   = Xbf;                                // X dead after gemm1

  convert_f32_bf16<<<4096, 256, 0, stream>>>(hidden, Xbf, 4096 * 1024);
  transpose_pack<<<dim3(16, 16), 256, 0, stream>>>(wq, Wqkvt, 1024, 0);
  transpose_pack<<<dim3(4, 16),  256, 0, stream>>>(wk, Wqkvt, 256, 1024);
  transpose_pack<<<dim3(4, 16),  256, 0, stream>>>(wv, Wqkvt, 256, 1280);
  transpose_pack<<<dim3(16, 16), 256, 0, stream>>>(wo, Wot, 1024, 0);

  gemm_bt<true><<<dim3(12, 32), 256, 0, stream>>>(Xbf, Wqkvt, QKV, 4096, 1536, 1024, 1536);
  qk_norm<<<20480, 256, 0, stream>>>(QKV, qw, kw);
  transpose_v<<<dim3(32, 8), 256, 0, stream>>>(QKV, Vtg);      // after gemm1 (aliases Wqkvt)
  mask_flags<<<dim3(32, 32), 256, 0, stream>>>(mask, flags);   // after gemm1 (aliases Wqkvt)
  flash_attn<<<dim3(32, 32), 256, 0, stream>>>(QKV, Vtg, mask, flags, Obf);
  gemm_bt<false><<<dim3(8, 32), 256, 0, stream>>>(Obf, Wot, d_out, 4096, 1024, 1024, 1024);
}

// Round 3
// 175.473 us; speedup vs baseline: 1.5281x; 1.3462x over previous
//
#include <hip/hip_runtime.h>
#include <hip/hip_bf16.h>

// MTPAttention: B=2,S=2048,HS=1024,H=16,KV=4,DH=64, full attention + additive mask.
// Pipeline: convert/pack -> GEMM(QKV) -> qk_norm(+fold scale) -> V-transpose(k-permuted) ->
//           mask tile-zero bitmap -> flash attn (2-phase pipelined) -> GEMM(O@wo).

typedef __attribute__((ext_vector_type(8))) short short8_t;   // 8 x bf16 (4 VGPR)
typedef __attribute__((ext_vector_type(4))) float f32x4_t;    // MFMA acc

__device__ __forceinline__ unsigned short f2bf_bits(float x) {
  unsigned int u = __float_as_uint(x);
  unsigned int r = u + 0x7fff + ((u >> 16) & 1);   // RNE (inputs finite)
  return (unsigned short)(r >> 16);
}
__device__ __forceinline__ float bf2f_bits(unsigned short b) {
  return __uint_as_float(((unsigned int)b) << 16);
}
__device__ __forceinline__ unsigned int cvt_pk_bf16(float lo, float hi) {
  unsigned int r;
  asm("v_cvt_pk_bf16_f32 %0, %1, %2" : "=v"(r) : "v"(lo), "v"(hi));
  return r;
}

__device__ __forceinline__ void async16(void* lds, const void* g) {
  __builtin_amdgcn_global_load_lds(
      (const __attribute__((address_space(1))) void*)g,
      (__attribute__((address_space(3))) void*)lds, 16, 0, 0);
}

// ---------------- convert fp32 -> bf16 (vectorized) ----------------
__global__ __launch_bounds__(256) void convert_f32_bf16(
    const float* __restrict__ in, unsigned short* __restrict__ out, int n) {
  int i = (blockIdx.x * 256 + threadIdx.x) * 4;
  if (i >= n) return;
  float4 v = *(const float4*)(in + i);
  ushort4 o;
  o.x = f2bf_bits(v.x); o.y = f2bf_bits(v.y);
  o.z = f2bf_bits(v.z); o.w = f2bf_bits(v.w);
  *(ushort4*)(out + i) = o;
}

// ---------------- transpose + convert weights: W[K=1024][Nsrc] -> Wt[n_off+n][k] bf16 ----------------
__global__ __launch_bounds__(256) void transpose_pack(
    const float* __restrict__ W, unsigned short* __restrict__ Wt, int Nsrc, int n_off) {
  __shared__ unsigned short T[64][72];
  const int tn = blockIdx.x * 64, tk = blockIdx.y * 64;
  for (int e = threadIdx.x; e < 4096; e += 256) {
    int kk = e >> 6, nn = e & 63;
    T[nn][kk] = f2bf_bits(W[(size_t)(tk + kk) * Nsrc + tn + nn]);   // coalesced read
  }
  __syncthreads();
  for (int e = threadIdx.x; e < 4096; e += 256) {
    int nn = e >> 6, kk = e & 63;
    Wt[(size_t)(n_off + tn + nn) * 1024 + tk + kk] = T[nn][kk];     // coalesced write
  }
}

// ---- transpose V with k-permutation within each 64-block: Vt[bk*64+d][st + (s&15)*4+(s>>4)] = V[s][d]
// (flash's P is packed with k' = lr*4+n; pi(k') = (k'&3)*16 + (k'>>2) maps back to original k)
__global__ __launch_bounds__(256) void transpose_v(
    const unsigned short* __restrict__ qkv, unsigned short* __restrict__ vt) {
  __shared__ unsigned short T[64][72];
  const int tid = threadIdx.x;
  const int st = blockIdx.x * 64, bk = blockIdx.y;      // bk = b*4+kvh
  const int b = bk >> 2, kvh = bk & 3;
  const unsigned short* src = qkv + (size_t)(b * 2048 + st) * 1536 + 1280 + kvh * 64;
  for (int e = tid; e < 4096; e += 256) {
    int s = e >> 6, d = e & 63;
    T[d][s] = src[(size_t)s * 1536 + d];                // coalesced read
  }
  __syncthreads();
  unsigned short* dst = vt + (size_t)bk * 64 * 2048 + st;
  for (int e = tid; e < 4096; e += 256) {
    int d = e >> 6, s = e & 63;
    dst[(size_t)d * 2048 + ((s & 15) * 4 + (s >> 4))] = T[d][s];   // 128B-contained permute
  }
}

// ---------------- mask tile-zero bitmap: flags[qt*32+kt] = any nonzero in 64x64 tile ----------------
__global__ __launch_bounds__(256) void mask_flags(
    const float* __restrict__ mask, int* __restrict__ flags) {
  const int tid = threadIdx.x;
  const int bq = blockIdx.y * 64, bk = blockIdx.x * 64;
  bool nz = false;
  #pragma unroll
  for (int i = 0; i < 4; ++i) {
    int e = (i * 256 + tid) * 4;
    int r = e >> 6, c = e & 63;
    float4 v = *(const float4*)(mask + (size_t)(bq + r) * 2048 + bk + c);
    nz |= (v.x != 0.f) | (v.y != 0.f) | (v.z != 0.f) | (v.w != 0.f);
  }
  __shared__ int s;
  if (tid == 0) s = 0;
  __syncthreads();
  if (__any((int)nz) && (tid & 63) == 0) atomicOr(&s, 1);
  __syncthreads();
  if (tid == 0) flags[blockIdx.y * gridDim.x + blockIdx.x] = s;
}

// ---------------- bf16 GEMM: C[M][N] = A[M][K] * Bt[N][K]^T  (m97 structure) ----------------
template <bool OUT_BF16>
__global__ __launch_bounds__(256) void gemm_bt(
    const unsigned short* __restrict__ A, const unsigned short* __restrict__ Bt,
    void* __restrict__ Cp, int M, int N, int K, int ldc) {
  __shared__ unsigned short As[128 * 32];
  __shared__ unsigned short Bs[128 * 32];
  const int tid = threadIdx.x;
  const int w = tid >> 6, l = tid & 63, lr = l & 15, lg = l >> 4;
  const int bm = blockIdx.y * 128, bn = blockIdx.x * 128;
  const int wrow = (w >> 1) * 64, wcol = (w & 1) * 64;

  f32x4_t acc[4][4] = {};

  for (int k0 = 0; k0 < K; k0 += 32) {
    __syncthreads();
    #pragma unroll
    for (int i = 0; i < 2; ++i) {
      int c = i * 4 + w;
      const unsigned short* ga = A + (size_t)(bm + c * 16 + (l >> 2)) * K + k0 + (l & 3) * 8;
      async16(As + c * 512, ga);
      const unsigned short* gb = Bt + (size_t)(bn + c * 16 + (l >> 2)) * K + k0 + (l & 3) * 8;
      async16(Bs + c * 512, gb);
    }
    __syncthreads();
    short8_t af[4], bfr[4];
    #pragma unroll
    for (int m = 0; m < 4; ++m)
      af[m] = *(const short8_t*)(As + (wrow + m * 16 + lr) * 32 + lg * 8);
    #pragma unroll
    for (int n = 0; n < 4; ++n)
      bfr[n] = *(const short8_t*)(Bs + (wcol + n * 16 + lr) * 32 + lg * 8);
    #pragma unroll
    for (int m = 0; m < 4; ++m)
      #pragma unroll
      for (int n = 0; n < 4; ++n)
        acc[m][n] = __builtin_amdgcn_mfma_f32_16x16x32_bf16(af[m], bfr[n], acc[m][n], 0, 0, 0);
  }

  #pragma unroll
  for (int m = 0; m < 4; ++m)
    #pragma unroll
    for (int n = 0; n < 4; ++n)
      #pragma unroll
      for (int j = 0; j < 4; ++j) {
        int row = bm + wrow + m * 16 + lg * 4 + j;
        int col = bn + wcol + n * 16 + lr;
        float v = acc[m][n][j];
        if (OUT_BF16) ((unsigned short*)Cp)[(size_t)row * ldc + col] = f2bf_bits(v);
        else          ((float*)Cp)[(size_t)row * ldc + col] = v;
      }
}

// ---------------- RMS norm over DH=64; Q heads also fold in SCALE=0.125 ----------------
__global__ __launch_bounds__(256) void qk_norm(
    unsigned short* __restrict__ qkv, const float* __restrict__ qw, const float* __restrict__ kw) {
  int gid = blockIdx.x * 4 + (threadIdx.x >> 6);
  int l = threadIdx.x & 63;
  int row = gid / 20, seg = gid - row * 20;        // 0..15 = Q heads, 16..19 = K heads
  size_t idx = (size_t)row * 1536 + seg * 64 + l;
  float x = bf2f_bits(qkv[idx]);
  float ss = x * x;
  #pragma unroll
  for (int m = 1; m < 64; m <<= 1) ss += __shfl_xor(ss, m, 64);
  float r = rsqrtf(ss * (1.0f / 64.0f) + 1e-6f);
  float wv = (seg < 16) ? qw[l] * 0.125f : kw[l];   // fold attention scale into Q
  qkv[idx] = f2bf_bits(x * r * wv);
}

// ---------------- flash attention: block = (64-row q-tile, b, hq); 2-phase pipeline ----------------
__global__ __launch_bounds__(256, 4) void flash_attn(
    const unsigned short* __restrict__ qkv, const unsigned short* __restrict__ vtg,
    const float* __restrict__ mask, const int* __restrict__ flags,
    unsigned short* __restrict__ O) {
  const int qt = blockIdx.x, bh = blockIdx.y;
  const int b = bh >> 4, hq = bh & 15, kvh = hq >> 2;
  const int tid = threadIdx.x, w = tid >> 6, l = tid & 63, lr = l & 15, lg = l >> 4;

  // linear LDS + XOR swizzle (16B units): LDS(row, cc) holds global(row, cc ^ (row&7))
  __shared__ unsigned short Ks[2][64 * 64];   // [k][d]  8KB x2
  __shared__ unsigned short Vs[2][64 * 64];   // [d][k'] 8KB x2 (k' pre-permuted in global Vt)
  __shared__ unsigned short Ps[64 * 64];      // [q][k'] 8KB, wave-private rows

  const unsigned short* Qg = qkv + (size_t)(b * 2048 + qt * 64) * 1536 + hq * 64;
  const unsigned short* Kg = qkv + (size_t)(b * 2048) * 1536 + 1024 + kvh * 64;
  const unsigned short* Vg = vtg + (size_t)(b * 4 + kvh) * 64 * 2048;
  const float* Mg = mask + (size_t)(qt * 64) * 2048;
  const int* Fp = flags + qt * 32;

  // Q fragments straight from global (once per block)
  short8_t qf[2];
  {
    const unsigned short* qrow = Qg + (size_t)(w * 16 + lr) * 1536 + lg * 8;
    qf[0] = *(const short8_t*)(qrow);
    qf[1] = *(const short8_t*)(qrow + 32);
  }

  // constant ones B-fragment: col 0 = 1.0 for all k -> 5th acc frag carries row sums
  short8_t vb1;
  #pragma unroll
  for (int e = 0; e < 8; ++e) vb1[e] = (lr == 0) ? (short)0x3f80 : (short)0;

  // stage one 64x64 K tile + one 64x64 V tile into buffer bi (inverse-swizzled source)
  auto stage = [&](int kt2, int bi) {
    #pragma unroll
    for (int it = 0; it < 2; ++it) {
      int c = it * 256 + tid;                    // 16B chunk id 0..511
      int r = c >> 3, cc = (c & 7) ^ (r & 7);    // pre-swizzled source column
      async16(&Ks[bi][it * 2048 + w * 512],
              Kg + (size_t)(kt2 * 64 + r) * 1536 + cc * 8);
      async16(&Vs[bi][it * 2048 + w * 512],
              Vg + (size_t)r * 2048 + kt2 * 64 + cc * 8);
    }
  };

  f32x4_t oacc[5] = {};                          // [0..3]=O cols, [4]=row-sum column
  float mrun = -INFINITY;
  const float L2E = 1.44269504f;

  stage(0, 0);

  for (int kt = 0; kt < 32; ++kt) {
    __syncthreads();                             // vmcnt(0)+barrier: buf ready, prev reads done
    if (kt < 31) stage(kt + 1, (kt + 1) & 1);    // prefetch in flight across compute
    const int cur = kt & 1;

    // S = Q K^T  (scale pre-folded into Q)
    f32x4_t sacc[4] = {};
    #pragma unroll
    for (int kd = 0; kd < 2; ++kd)
      #pragma unroll
      for (int n = 0; n < 4; ++n) {
        int kr = n * 16 + lr;
        short8_t kf = *(const short8_t*)(&Ks[cur][kr * 64 + ((kd * 4 + lg) ^ (kr & 7)) * 8]);
        sacc[n] = __builtin_amdgcn_mfma_f32_16x16x32_bf16(qf[kd], kf, sacc[n], 0, 0, 0);
      }

    float s[4][4];
    if (Fp[kt]) {
      #pragma unroll
      for (int n = 0; n < 4; ++n)
        #pragma unroll
        for (int j = 0; j < 4; ++j)
          s[n][j] = sacc[n][j]
                  + Mg[(size_t)(w * 16 + lg * 4 + j) * 2048 + kt * 64 + n * 16 + lr];
    } else {
      #pragma unroll
      for (int n = 0; n < 4; ++n)
        #pragma unroll
        for (int j = 0; j < 4; ++j) s[n][j] = sacc[n][j];
    }

    // per-wave tile max (a per-row upper bound suffices; scores bounded post-norm)
    float tm = s[0][0];
    #pragma unroll
    for (int n = 0; n < 4; ++n)
      #pragma unroll
      for (int j = 0; j < 4; ++j) tm = fmaxf(tm, s[n][j]);
    #pragma unroll
    for (int m = 1; m < 64; m <<= 1) tm = fmaxf(tm, __shfl_xor(tm, m, 64));

    if (tm > mrun + 8.f) {                       // deferred rescale (wave-uniform)
      float al = exp2f((mrun - tm) * L2E);
      mrun = tm;
      #pragma unroll
      for (int nd = 0; nd < 5; ++nd) {
        f32x4_t t = oacc[nd];
        #pragma unroll
        for (int j = 0; j < 4; ++j) t[j] *= al;
        oacc[nd] = t;
      }
    }
    const float nm = -mrun * L2E;

    float e4[4][4];
    #pragma unroll
    for (int n = 0; n < 4; ++n)
      #pragma unroll
      for (int j = 0; j < 4; ++j)
        e4[n][j] = exp2f(fmaf(s[n][j], L2E, nm));

    // pack P at permuted col' = lr*4+n : 2x cvt_pk + one 8B write per row (swizzled)
    #pragma unroll
    for (int j = 0; j < 4; ++j) {
      unsigned int u0 = cvt_pk_bf16(e4[0][j], e4[1][j]);
      unsigned int u1 = cvt_pk_bf16(e4[2][j], e4[3][j]);
      int pr = w * 16 + lg * 4 + j;
      *(uint2*)(&Ps[pr * 64 + (((lr * 8) ^ ((pr & 7) << 4)) >> 1)]) = make_uint2(u0, u1);
    }
    // wave-private P round-trip: no barrier needed (lgkmcnt ordering only)

    // O += P V  (+ ones column -> running sum)
    #pragma unroll
    for (int kd = 0; kd < 2; ++kd) {
      int pr = w * 16 + lr;
      short8_t pa = *(const short8_t*)(
          &Ps[pr * 64 + (((kd * 64 + lg * 16) ^ ((pr & 7) << 4)) >> 1)]);
      #pragma unroll
      for (int nd = 0; nd < 4; ++nd) {
        int vr = nd * 16 + lr;
        short8_t vb = *(const short8_t*)(&Vs[cur][vr * 64 + ((kd * 4 + lg) ^ (vr & 7)) * 8]);
        oacc[nd] = __builtin_amdgcn_mfma_f32_16x16x32_bf16(pa, vb, oacc[nd], 0, 0, 0);
      }
      oacc[4] = __builtin_amdgcn_mfma_f32_16x16x32_bf16(pa, vb1, oacc[4], 0, 0, 0);
    }
  }

  // epilogue: sums live in lanes lr==0 of frag 4; broadcast within row group
  float rln[4];
  #pragma unroll
  for (int j = 0; j < 4; ++j) rln[j] = 1.0f / __shfl(oacc[4][j], l & 48, 64);
  #pragma unroll
  for (int nd = 0; nd < 4; ++nd)
    #pragma unroll
    for (int j = 0; j < 4; ++j) {
      size_t row = (size_t)(b * 2048 + qt * 64 + w * 16 + lg * 4 + j);
      O[row * 1024 + hq * 64 + nd * 16 + lr] = f2bf_bits(oacc[nd][j] * rln[j]);
    }
}

extern "C" void kernel_launch(void* const* d_in, const int* in_sizes, int n_in,
                              void* d_out, int out_size, void* d_ws, size_t ws_size,
                              hipStream_t stream) {
  const float* hidden = (const float*)d_in[0];
  const float* mask   = (const float*)d_in[1];
  const float* wq     = (const float*)d_in[2];
  const float* wk     = (const float*)d_in[3];
  const float* wv     = (const float*)d_in[4];
  const float* wo     = (const float*)d_in[5];
  const float* qw     = (const float*)d_in[6];
  const float* kw     = (const float*)d_in[7];

  char* ws = (char*)d_ws;
  unsigned short* Xbf   = (unsigned short*)(ws);              // [4096][1024] bf16
  unsigned short* Wqkvt = (unsigned short*)(ws +  8388608);   // [1536][1024] bf16 (dead after gemm1)
  unsigned short* Wot   = (unsigned short*)(ws + 11534336);   // [1024][1024] bf16
  unsigned short* QKV   = (unsigned short*)(ws + 13631488);   // [4096][1536] bf16
  unsigned short* Vtg   = Wqkvt;                              // [8*64][2048] bf16, aliases Wqkvt
  int*            flags = (int*)(ws + 10485760);              // [1024], aliases Wqkvt tail
  unsigned short* Obf   = Xbf;                                // X dead after gemm1

  convert_f32_bf16<<<4096, 256, 0, stream>>>(hidden, Xbf, 4096 * 1024);
  transpose_pack<<<dim3(16, 16), 256, 0, stream>>>(wq, Wqkvt, 1024, 0);
  transpose_pack<<<dim3(4, 16),  256, 0, stream>>>(wk, Wqkvt, 256, 1024);
  transpose_pack<<<dim3(4, 16),  256, 0, stream>>>(wv, Wqkvt, 256, 1280);
  transpose_pack<<<dim3(16, 16), 256, 0, stream>>>(wo, Wot, 1024, 0);

  gemm_bt<true><<<dim3(12, 32), 256, 0, stream>>>(Xbf, Wqkvt, QKV, 4096, 1536, 1024, 1536);
  qk_norm<<<20480, 256, 0, stream>>>(QKV, qw, kw);
  transpose_v<<<dim3(32, 8), 256, 0, stream>>>(QKV, Vtg);      // after gemm1 (aliases Wqkvt)
  mask_flags<<<dim3(32, 32), 256, 0, stream>>>(mask, flags);   // after gemm1 (aliases Wqkvt)
  flash_attn<<<dim3(32, 32), 256, 0, stream>>>(QKV, Vtg, mask, flags, Obf);
  gemm_bt<false><<<dim3(8, 32), 256, 0, stream>>>(Obf, Wot, d_out, 4096, 1024, 1024, 1024);
}

// Round 4
// 172.595 us; speedup vs baseline: 1.5536x; 1.0167x over previous
//
#include <hip/hip_runtime.h>
#include <hip/hip_bf16.h>

// MTPAttention: B=2,S=2048,HS=1024,H=16,KV=4,DH=64, full attention + additive mask.
// Pipeline: convert/pack -> GEMM(QKV)+fused qk-norm -> V-transpose(k-permuted) ->
//           mask tile-zero bitmap -> flash attn (32 q-rows/wave, 2-phase) -> GEMM(O@wo).

typedef __attribute__((ext_vector_type(8))) short short8_t;   // 8 x bf16 (4 VGPR)
typedef __attribute__((ext_vector_type(4))) float f32x4_t;    // MFMA acc

__device__ __forceinline__ unsigned short f2bf_bits(float x) {
  unsigned int u = __float_as_uint(x);
  unsigned int r = u + 0x7fff + ((u >> 16) & 1);   // RNE (inputs finite)
  return (unsigned short)(r >> 16);
}
__device__ __forceinline__ float bf2f_bits(unsigned short b) {
  return __uint_as_float(((unsigned int)b) << 16);
}
__device__ __forceinline__ unsigned int cvt_pk_bf16(float lo, float hi) {
  unsigned int r;
  asm("v_cvt_pk_bf16_f32 %0, %1, %2" : "=v"(r) : "v"(lo), "v"(hi));
  return r;
}

__device__ __forceinline__ void async16(void* lds, const void* g) {
  __builtin_amdgcn_global_load_lds(
      (const __attribute__((address_space(1))) void*)g,
      (__attribute__((address_space(3))) void*)lds, 16, 0, 0);
}

// ---------------- convert fp32 -> bf16 (vectorized) ----------------
__global__ __launch_bounds__(256) void convert_f32_bf16(
    const float* __restrict__ in, unsigned short* __restrict__ out, int n) {
  int i = (blockIdx.x * 256 + threadIdx.x) * 4;
  if (i >= n) return;
  float4 v = *(const float4*)(in + i);
  ushort4 o;
  o.x = f2bf_bits(v.x); o.y = f2bf_bits(v.y);
  o.z = f2bf_bits(v.z); o.w = f2bf_bits(v.w);
  *(ushort4*)(out + i) = o;
}

// ---------------- transpose + convert weights: W[K=1024][Nsrc] -> Wt[n_off+n][k] bf16 ----------------
__global__ __launch_bounds__(256) void transpose_pack(
    const float* __restrict__ W, unsigned short* __restrict__ Wt, int Nsrc, int n_off) {
  __shared__ unsigned short T[64][72];
  const int tn = blockIdx.x * 64, tk = blockIdx.y * 64;
  for (int e = threadIdx.x; e < 4096; e += 256) {
    int kk = e >> 6, nn = e & 63;
    T[nn][kk] = f2bf_bits(W[(size_t)(tk + kk) * Nsrc + tn + nn]);   // coalesced read
  }
  __syncthreads();
  for (int e = threadIdx.x; e < 4096; e += 256) {
    int nn = e >> 6, kk = e & 63;
    Wt[(size_t)(n_off + tn + nn) * 1024 + tk + kk] = T[nn][kk];     // coalesced write
  }
}

// ---- transpose V with k-permutation within each 64-block: Vt[bk*64+d][st + (s&15)*4+(s>>4)] = V[s][d]
__global__ __launch_bounds__(256) void transpose_v(
    const unsigned short* __restrict__ qkv, unsigned short* __restrict__ vt) {
  __shared__ unsigned short T[64][72];
  const int tid = threadIdx.x;
  const int st = blockIdx.x * 64, bk = blockIdx.y;      // bk = b*4+kvh
  const int b = bk >> 2, kvh = bk & 3;
  const unsigned short* src = qkv + (size_t)(b * 2048 + st) * 1536 + 1280 + kvh * 64;
  for (int e = tid; e < 4096; e += 256) {
    int s = e >> 6, d = e & 63;
    T[d][s] = src[(size_t)s * 1536 + d];                // coalesced read
  }
  __syncthreads();
  unsigned short* dst = vt + (size_t)bk * 64 * 2048 + st;
  for (int e = tid; e < 4096; e += 256) {
    int d = e >> 6, s = e & 63;
    dst[(size_t)d * 2048 + ((s & 15) * 4 + (s >> 4))] = T[d][s];   // 128B-contained permute
  }
}

// ---------------- mask tile-zero bitmap: flags[qt*32+kt] = any nonzero in 64x64 tile ----------------
__global__ __launch_bounds__(256) void mask_flags(
    const float* __restrict__ mask, int* __restrict__ flags) {
  const int tid = threadIdx.x;
  const int bq = blockIdx.y * 64, bk = blockIdx.x * 64;
  bool nz = false;
  #pragma unroll
  for (int i = 0; i < 4; ++i) {
    int e = (i * 256 + tid) * 4;
    int r = e >> 6, c = e & 63;
    float4 v = *(const float4*)(mask + (size_t)(bq + r) * 2048 + bk + c);
    nz |= (v.x != 0.f) | (v.y != 0.f) | (v.z != 0.f) | (v.w != 0.f);
  }
  __shared__ int s;
  if (tid == 0) s = 0;
  __syncthreads();
  if (__any((int)nz) && (tid & 63) == 0) atomicOr(&s, 1);
  __syncthreads();
  if (tid == 0) flags[blockIdx.y * gridDim.x + blockIdx.x] = s;
}

// ------- bf16 GEMM: C[M][N] = A[M][K] * Bt[N][K]^T; optional fused per-64-col RMS norm -------
template <bool OUT_BF16, bool QKNORM>
__global__ __launch_bounds__(256) void gemm_bt(
    const unsigned short* __restrict__ A, const unsigned short* __restrict__ Bt,
    void* __restrict__ Cp, int M, int N, int K, int ldc,
    const float* __restrict__ qw, const float* __restrict__ kw) {
  __shared__ unsigned short As[128 * 32];
  __shared__ unsigned short Bs[128 * 32];
  const int tid = threadIdx.x;
  const int w = tid >> 6, l = tid & 63, lr = l & 15, lg = l >> 4;
  const int bm = blockIdx.y * 128, bn = blockIdx.x * 128;
  const int wrow = (w >> 1) * 64, wcol = (w & 1) * 64;

  f32x4_t acc[4][4] = {};

  for (int k0 = 0; k0 < K; k0 += 32) {
    __syncthreads();
    #pragma unroll
    for (int i = 0; i < 2; ++i) {
      int c = i * 4 + w;
      const unsigned short* ga = A + (size_t)(bm + c * 16 + (l >> 2)) * K + k0 + (l & 3) * 8;
      async16(As + c * 512, ga);
      const unsigned short* gb = Bt + (size_t)(bn + c * 16 + (l >> 2)) * K + k0 + (l & 3) * 8;
      async16(Bs + c * 512, gb);
    }
    __syncthreads();
    short8_t af[4], bfr[4];
    #pragma unroll
    for (int m = 0; m < 4; ++m)
      af[m] = *(const short8_t*)(As + (wrow + m * 16 + lr) * 32 + lg * 8);
    #pragma unroll
    for (int n = 0; n < 4; ++n)
      bfr[n] = *(const short8_t*)(Bs + (wcol + n * 16 + lr) * 32 + lg * 8);
    #pragma unroll
    for (int m = 0; m < 4; ++m)
      #pragma unroll
      for (int n = 0; n < 4; ++n)
        acc[m][n] = __builtin_amdgcn_mfma_f32_16x16x32_bf16(af[m], bfr[n], acc[m][n], 0, 0, 0);
  }

  // fused RMS norm over the wave's 64-col head segment (Q: seg<16 with 0.125 fold, K: 16..19)
  if constexpr (QKNORM) {
    int seg = (bn + wcol) >> 6;
    if (seg < 20) {
      const float* wseg = (seg < 16) ? qw : kw;
      float wv[4];
      #pragma unroll
      for (int n = 0; n < 4; ++n) {
        wv[n] = wseg[n * 16 + lr];
        if (seg < 16) wv[n] *= 0.125f;
      }
      #pragma unroll
      for (int m = 0; m < 4; ++m)
        #pragma unroll
        for (int j = 0; j < 4; ++j) {
          float ss = acc[m][0][j] * acc[m][0][j];
          #pragma unroll
          for (int n = 1; n < 4; ++n) ss += acc[m][n][j] * acc[m][n][j];
          #pragma unroll
          for (int x = 1; x < 16; x <<= 1) ss += __shfl_xor(ss, x, 64);
          float rinv = rsqrtf(ss * (1.0f / 64.0f) + 1e-6f);
          #pragma unroll
          for (int n = 0; n < 4; ++n) acc[m][n][j] *= rinv * wv[n];
        }
    }
  }

  #pragma unroll
  for (int m = 0; m < 4; ++m)
    #pragma unroll
    for (int n = 0; n < 4; ++n)
      #pragma unroll
      for (int j = 0; j < 4; ++j) {
        int row = bm + wrow + m * 16 + lg * 4 + j;
        int col = bn + wcol + n * 16 + lr;
        float v = acc[m][n][j];
        if (OUT_BF16) ((unsigned short*)Cp)[(size_t)row * ldc + col] = f2bf_bits(v);
        else          ((float*)Cp)[(size_t)row * ldc + col] = v;
      }
}

// ------- flash attention: block = (128-row q-tile, b, hq); 32 q-rows/wave; 2-phase -------
__global__ __launch_bounds__(256, 4) void flash_attn(
    const unsigned short* __restrict__ qkv, const unsigned short* __restrict__ vtg,
    const float* __restrict__ mask, const int* __restrict__ flags,
    unsigned short* __restrict__ O) {
  const int qt = blockIdx.x, bh = blockIdx.y;         // qt 0..15 (128 rows each)
  const int b = bh >> 4, hq = bh & 15, kvh = hq >> 2;
  const int tid = threadIdx.x, w = tid >> 6, l = tid & 63, lr = l & 15, lg = l >> 4;

  // linear LDS + XOR swizzle (16B units): LDS(row, cc) holds global(row, cc ^ (row&7))
  __shared__ unsigned short Ks[2][64 * 64];   // [k][d]   8KB x2
  __shared__ unsigned short Vs[2][64 * 64];   // [d][k']  8KB x2 (k' pre-permuted)
  __shared__ unsigned short Ps[128 * 64];     // [q][k'] 16KB, wave-private rows

  const unsigned short* Qg = qkv + (size_t)(b * 2048 + qt * 128) * 1536 + hq * 64;
  const unsigned short* Kg = qkv + (size_t)(b * 2048) * 1536 + 1024 + kvh * 64;
  const unsigned short* Vg = vtg + (size_t)(b * 4 + kvh) * 64 * 2048;
  const float* Mg = mask + (size_t)(qt * 128) * 2048;
  const int* Fp = flags + qt * 64;                    // two 64-row flag strips

  // Q fragments straight from global (once per block): wave w owns rows w*32..w*32+31
  short8_t qf[2][2];
  #pragma unroll
  for (int mr = 0; mr < 2; ++mr) {
    const unsigned short* qrow = Qg + (size_t)(w * 32 + mr * 16 + lr) * 1536 + lg * 8;
    qf[mr][0] = *(const short8_t*)(qrow);
    qf[mr][1] = *(const short8_t*)(qrow + 32);
  }

  // constant ones B-fragment: col 0 = 1.0 -> sum column
  short8_t vb1;
  #pragma unroll
  for (int e = 0; e < 8; ++e) vb1[e] = (lr == 0) ? (short)0x3f80 : (short)0;

  auto stage = [&](int kt2, int bi) {
    #pragma unroll
    for (int it = 0; it < 2; ++it) {
      int c = it * 256 + tid;                    // 16B chunk id 0..511
      int r = c >> 3, cc = (c & 7) ^ (r & 7);    // pre-swizzled source column
      async16(&Ks[bi][it * 2048 + w * 512],
              Kg + (size_t)(kt2 * 64 + r) * 1536 + cc * 8);
      async16(&Vs[bi][it * 2048 + w * 512],
              Vg + (size_t)r * 2048 + kt2 * 64 + cc * 8);
    }
  };

  f32x4_t oacc[2][5] = {};                       // per mrow: [0..3]=O cols, [4]=sum col
  float mrun = -INFINITY;
  const float L2E = 1.44269504f;

  stage(0, 0);

  for (int kt = 0; kt < 32; ++kt) {
    __syncthreads();                             // buf ready (vmcnt drained), prev reads done
    if (kt < 31) stage(kt + 1, (kt + 1) & 1);
    const int cur = kt & 1;

    // S = Q K^T: each kf read feeds both mrow MFMAs
    f32x4_t sacc[2][4] = {};
    #pragma unroll
    for (int kd = 0; kd < 2; ++kd)
      #pragma unroll
      for (int n = 0; n < 4; ++n) {
        int kr = n * 16 + lr;
        short8_t kf = *(const short8_t*)(&Ks[cur][kr * 64 + ((kd * 4 + lg) ^ (kr & 7)) * 8]);
        #pragma unroll
        for (int mr = 0; mr < 2; ++mr)
          sacc[mr][n] = __builtin_amdgcn_mfma_f32_16x16x32_bf16(qf[mr][kd], kf, sacc[mr][n], 0, 0, 0);
      }

    float s[2][4][4];
    if (Fp[kt] | Fp[32 + kt]) {
      #pragma unroll
      for (int mr = 0; mr < 2; ++mr)
        #pragma unroll
        for (int n = 0; n < 4; ++n)
          #pragma unroll
          for (int j = 0; j < 4; ++j)
            s[mr][n][j] = sacc[mr][n][j]
                + Mg[(size_t)(w * 32 + mr * 16 + lg * 4 + j) * 2048 + kt * 64 + n * 16 + lr];
    } else {
      #pragma unroll
      for (int mr = 0; mr < 2; ++mr)
        #pragma unroll
        for (int n = 0; n < 4; ++n)
          #pragma unroll
          for (int j = 0; j < 4; ++j) s[mr][n][j] = sacc[mr][n][j];
    }

    // wave tile max (upper bound per row suffices)
    float tm = s[0][0][0];
    #pragma unroll
    for (int mr = 0; mr < 2; ++mr)
      #pragma unroll
      for (int n = 0; n < 4; ++n)
        #pragma unroll
        for (int j = 0; j < 4; ++j) tm = fmaxf(tm, s[mr][n][j]);
    #pragma unroll
    for (int x = 1; x < 64; x <<= 1) tm = fmaxf(tm, __shfl_xor(tm, x, 64));

    if (tm > mrun + 8.f) {                       // deferred rescale (wave-uniform)
      float al = exp2f((mrun - tm) * L2E);
      mrun = tm;
      #pragma unroll
      for (int mr = 0; mr < 2; ++mr)
        #pragma unroll
        for (int nd = 0; nd < 5; ++nd) {
          f32x4_t t = oacc[mr][nd];
          #pragma unroll
          for (int j = 0; j < 4; ++j) t[j] *= al;
          oacc[mr][nd] = t;
        }
    }
    const float nm = -mrun * L2E;

    // exp + pack P (col' = lr*4+n permuted order, matches pre-permuted V)
    #pragma unroll
    for (int mr = 0; mr < 2; ++mr)
      #pragma unroll
      for (int j = 0; j < 4; ++j) {
        float e0 = exp2f(fmaf(s[mr][0][j], L2E, nm));
        float e1 = exp2f(fmaf(s[mr][1][j], L2E, nm));
        float e2 = exp2f(fmaf(s[mr][2][j], L2E, nm));
        float e3 = exp2f(fmaf(s[mr][3][j], L2E, nm));
        unsigned int u0 = cvt_pk_bf16(e0, e1);
        unsigned int u1 = cvt_pk_bf16(e2, e3);
        int pr = w * 32 + mr * 16 + lg * 4 + j;
        *(uint2*)(&Ps[pr * 64 + (((lr * 8) ^ ((pr & 7) << 4)) >> 1)]) = make_uint2(u0, u1);
      }
    // wave-private P round-trip: no barrier needed

    // O += P V (+ ones column); each vb read feeds both mrow MFMAs
    #pragma unroll
    for (int kd = 0; kd < 2; ++kd) {
      short8_t pa[2];
      #pragma unroll
      for (int mr = 0; mr < 2; ++mr) {
        int pr = w * 32 + mr * 16 + lr;
        pa[mr] = *(const short8_t*)(
            &Ps[pr * 64 + (((kd * 64 + lg * 16) ^ ((pr & 7) << 4)) >> 1)]);
      }
      #pragma unroll
      for (int nd = 0; nd < 4; ++nd) {
        int vr = nd * 16 + lr;
        short8_t vb = *(const short8_t*)(&Vs[cur][vr * 64 + ((kd * 4 + lg) ^ (vr & 7)) * 8]);
        #pragma unroll
        for (int mr = 0; mr < 2; ++mr)
          oacc[mr][nd] = __builtin_amdgcn_mfma_f32_16x16x32_bf16(pa[mr], vb, oacc[mr][nd], 0, 0, 0);
      }
      #pragma unroll
      for (int mr = 0; mr < 2; ++mr)
        oacc[mr][4] = __builtin_amdgcn_mfma_f32_16x16x32_bf16(pa[mr], vb1, oacc[mr][4], 0, 0, 0);
    }
  }

  // epilogue: sums live in lanes lr==0 of frag 4; broadcast within 16-lane row group
  #pragma unroll
  for (int mr = 0; mr < 2; ++mr) {
    float rln[4];
    #pragma unroll
    for (int j = 0; j < 4; ++j) rln[j] = 1.0f / __shfl(oacc[mr][4][j], l & 48, 64);
    #pragma unroll
    for (int nd = 0; nd < 4; ++nd)
      #pragma unroll
      for (int j = 0; j < 4; ++j) {
        size_t row = (size_t)(b * 2048 + qt * 128 + w * 32 + mr * 16 + lg * 4 + j);
        O[row * 1024 + hq * 64 + nd * 16 + lr] = f2bf_bits(oacc[mr][nd][j] * rln[j]);
      }
  }
}

extern "C" void kernel_launch(void* const* d_in, const int* in_sizes, int n_in,
                              void* d_out, int out_size, void* d_ws, size_t ws_size,
                              hipStream_t stream) {
  const float* hidden = (const float*)d_in[0];
  const float* mask   = (const float*)d_in[1];
  const float* wq     = (const float*)d_in[2];
  const float* wk     = (const float*)d_in[3];
  const float* wv     = (const float*)d_in[4];
  const float* wo     = (const float*)d_in[5];
  const float* qw     = (const float*)d_in[6];
  const float* kw     = (const float*)d_in[7];

  char* ws = (char*)d_ws;
  unsigned short* Xbf   = (unsigned short*)(ws);              // [4096][1024] bf16
  unsigned short* Wqkvt = (unsigned short*)(ws +  8388608);   // [1536][1024] bf16 (dead after gemm1)
  unsigned short* Wot   = (unsigned short*)(ws + 11534336);   // [1024][1024] bf16
  unsigned short* QKV   = (unsigned short*)(ws + 13631488);   // [4096][1536] bf16
  unsigned short* Vtg   = Wqkvt;                              // [8*64][2048] bf16, aliases Wqkvt
  int*            flags = (int*)(ws + 10485760);              // [1024], aliases Wqkvt tail
  unsigned short* Obf   = Xbf;                                // X dead after gemm1

  convert_f32_bf16<<<4096, 256, 0, stream>>>(hidden, Xbf, 4096 * 1024);
  transpose_pack<<<dim3(16, 16), 256, 0, stream>>>(wq, Wqkvt, 1024, 0);
  transpose_pack<<<dim3(4, 16),  256, 0, stream>>>(wk, Wqkvt, 256, 1024);
  transpose_pack<<<dim3(4, 16),  256, 0, stream>>>(wv, Wqkvt, 256, 1280);
  transpose_pack<<<dim3(16, 16), 256, 0, stream>>>(wo, Wot, 1024, 0);

  gemm_bt<true, true><<<dim3(12, 32), 256, 0, stream>>>(
      Xbf, Wqkvt, QKV, 4096, 1536, 1024, 1536, qw, kw);
  transpose_v<<<dim3(32, 8), 256, 0, stream>>>(QKV, Vtg);      // after gemm1 (aliases Wqkvt)
  mask_flags<<<dim3(32, 32), 256, 0, stream>>>(mask, flags);   // after gemm1 (aliases Wqkvt)
  flash_attn<<<dim3(16, 32), 256, 0, stream>>>(QKV, Vtg, mask, flags, Obf);
  gemm_bt<false, false><<<dim3(8, 32), 256, 0, stream>>>(
      Obf, Wot, d_out, 4096, 1024, 1024, 1024, nullptr, nullptr);
}